// Round 6
// baseline (975.533 us; speedup 1.0000x reference)
//
#include <hip/hip_runtime.h>
#include <hip/hip_bf16.h>

#define F 128

typedef __attribute__((ext_vector_type(8))) short short8;    // 8 bf16 = 4 VGPRs
typedef __attribute__((ext_vector_type(4))) float floatx4;   // MFMA C/D

__device__ __forceinline__ float bf_lo(unsigned u) { return __uint_as_float(u << 16); }
__device__ __forceinline__ float bf_hi(unsigned u) { return __uint_as_float(u & 0xffff0000u); }

// opaque zero: compiler cannot prove it's 0 -> blocks loop-invariant hoisting of
// the rep-amplified kernel bodies (measurement round R6). ~1 VALU op per use.
__device__ __forceinline__ int opaque_zero() {
  int z = 0;
  asm volatile("" : "+v"(z));
  return z;
}

// fp32 -> bf16 bits, round-to-nearest-even
__device__ __forceinline__ unsigned short f2bf(float x) {
  unsigned u = __float_as_uint(x);
  u += 0x7fffu + ((u >> 16) & 1u);
  return (unsigned short)(u >> 16);
}
__device__ __forceinline__ unsigned pack2(float a, float b) {
  return (unsigned)f2bf(a) | ((unsigned)f2bf(b) << 16);
}
__device__ __forceinline__ void add8(float* a, uint4 u) {
  a[0] += bf_lo(u.x); a[1] += bf_hi(u.x);
  a[2] += bf_lo(u.y); a[3] += bf_hi(u.y);
  a[4] += bf_lo(u.z); a[5] += bf_hi(u.z);
  a[6] += bf_lo(u.w); a[7] += bf_hi(u.w);
}

// -------- merged: dst histogram + x->bf16 convert + both weight transposes --------
__global__ __launch_bounds__(256) void k_pre(const int* __restrict__ dst, int* __restrict__ A,
                                             int E, int cb,
                                             const float* __restrict__ x,
                                             const float* __restrict__ Wl0,
                                             const float* __restrict__ Wr0,
                                             const float* __restrict__ Wl1,
                                             const float* __restrict__ Wr1,
                                             unsigned short* __restrict__ xb,
                                             unsigned short* __restrict__ WcatT0,
                                             unsigned short* __restrict__ WcatT1, int n4) {
  if (blockIdx.x < cb) {
    int e = blockIdx.x * 256 + threadIdx.x;
    if (e < E) atomicAdd(&A[dst[e]], 1);
    return;
  }
  int i = (blockIdx.x - cb) * 256 + threadIdx.x;
  if (i < n4) {
    float4 v = ((const float4*)x)[i];
    ((ushort4*)xb)[i] = make_ushort4(f2bf(v.x), f2bf(v.y), f2bf(v.z), f2bf(v.w));
  } else {
    int j = i - n4;
    if (j < 2 * 256 * F) {
      int layer = j >> 15;
      int jj = j & 32767;
      int n = jj >> 8, k = jj & 255;
      const float* Wl = layer ? Wl1 : Wl0;
      const float* Wr = layer ? Wr1 : Wr0;
      unsigned short* WT = layer ? WcatT1 : WcatT0;
      float v = (k < F) ? Wl[k * F + n] : Wr[(k - F) * F + n];
      WT[(size_t)n * 256 + k] = f2bf(v);
    }
  }
}

// -------- single-kernel exclusive scan: 49 co-resident blocks, ticket + flag --------
__global__ __launch_bounds__(1024) void k_scan(int* __restrict__ A, int* __restrict__ bsum,
                                               int* __restrict__ bases, int* __restrict__ ctl,
                                               int n, int nb) {
  __shared__ int wtot[16];
  __shared__ int lastS, sbase;
  int t = threadIdx.x, l = t & 63, w = t >> 6;
  int i = blockIdx.x * 1024 + t;
  int v = (i < n) ? A[i] : 0;
  int acc = v;
#pragma unroll
  for (int off = 1; off < 64; off <<= 1) {
    int u = __shfl_up(acc, off);
    if (l >= off) acc += u;
  }
  if (l == 63) wtot[w] = acc;
  __syncthreads();
  int woff = 0, total = 0;
#pragma unroll
  for (int ww = 0; ww < 16; ++ww) {
    total += wtot[ww];
    if (ww < w) woff += wtot[ww];
  }
  int local = woff + (acc - v);
  if (t == 0) {
    __hip_atomic_store(&bsum[blockIdx.x], total, __ATOMIC_RELEASE, __HIP_MEMORY_SCOPE_AGENT);
    int tk = __hip_atomic_fetch_add(&ctl[0], 1, __ATOMIC_ACQ_REL, __HIP_MEMORY_SCOPE_AGENT);
    lastS = (tk == nb - 1);
  }
  __syncthreads();
  if (lastS) {
    if (t < 64) {
      int bv = (t < nb) ? __hip_atomic_load(&bsum[t], __ATOMIC_ACQUIRE, __HIP_MEMORY_SCOPE_AGENT) : 0;
      int a2 = bv;
#pragma unroll
      for (int off = 1; off < 64; off <<= 1) {
        int u = __shfl_up(a2, off);
        if (t >= off) a2 += u;
      }
      if (t < nb)
        __hip_atomic_store(&bases[t], a2 - bv, __ATOMIC_RELAXED, __HIP_MEMORY_SCOPE_AGENT);
    }
    __syncthreads();
    if (t == 0) {
      __threadfence();
      __hip_atomic_store(&ctl[1], 1, __ATOMIC_RELEASE, __HIP_MEMORY_SCOPE_AGENT);
    }
  }
  if (t == 0) {
    while (__hip_atomic_load(&ctl[1], __ATOMIC_ACQUIRE, __HIP_MEMORY_SCOPE_AGENT) == 0) {}
    sbase = __hip_atomic_load(&bases[blockIdx.x], __ATOMIC_RELAXED, __HIP_MEMORY_SCOPE_AGENT);
  }
  __syncthreads();
  if (i < n) A[i] = local + sbase;
}

// -------- CSR fill: A becomes row-end (inclusive). Full-grid (one edge/thread). --------
__global__ __launch_bounds__(256) void k_fill(const int* __restrict__ srcT,
                                              const int* __restrict__ dst,
                                              int* __restrict__ A, int* __restrict__ adj, int E) {
  int e = blockIdx.x * 256 + threadIdx.x;
  if (e >= E) return;
  int s = srcT[e], d = dst[e];
  int slot = atomicAdd(&A[d], 1);
  adj[slot] = s;
}

// -------- mean aggregation v5 (+R6 rep amplification; idempotent) --------
template <bool BN>
__global__ __launch_bounds__(256) void k_gather(const unsigned short* __restrict__ xin,
                                                const int* __restrict__ A,
                                                const int* __restrict__ adj,
                                                unsigned short* __restrict__ aggb,
                                                const float* __restrict__ scale,
                                                const float* __restrict__ shift,
                                                unsigned short* __restrict__ xout, int N,
                                                int rep) {
  int d = blockIdx.x * 16 + (threadIdx.x >> 4);
  int ln = threadIdx.x & 15;
  if (d >= N) return;

  for (int r = 0; r < rep; ++r) {
    const uint4* xrows = (const uint4*)xin + opaque_zero();
    const int* adjr = adj + opaque_zero();

    float sc[8], sh[8];
    if (BN) {
      float4 a = ((const float4*)scale)[2 * ln];
      float4 b = ((const float4*)scale)[2 * ln + 1];
      float4 c = ((const float4*)shift)[2 * ln];
      float4 e4 = ((const float4*)shift)[2 * ln + 1];
      sc[0] = a.x; sc[1] = a.y; sc[2] = a.z; sc[3] = a.w;
      sc[4] = b.x; sc[5] = b.y; sc[6] = b.z; sc[7] = b.w;
      sh[0] = c.x; sh[1] = c.y; sh[2] = c.z; sh[3] = c.w;
      sh[4] = e4.x; sh[5] = e4.y; sh[6] = e4.z; sh[7] = e4.w;
    }

    if (BN) {
      uint4 u = xrows[(size_t)d * 16 + ln];
      float v[8];
      v[0] = bf_lo(u.x); v[1] = bf_hi(u.x); v[2] = bf_lo(u.y); v[3] = bf_hi(u.y);
      v[4] = bf_lo(u.z); v[5] = bf_hi(u.z); v[6] = bf_lo(u.w); v[7] = bf_hi(u.w);
#pragma unroll
      for (int j = 0; j < 8; ++j) v[j] = fmaxf(fmaf(v[j], sc[j], sh[j]), 0.f);
      uint4 o = make_uint4(pack2(v[0], v[1]), pack2(v[2], v[3]),
                           pack2(v[4], v[5]), pack2(v[6], v[7]));
      ((uint4*)xout)[(size_t)d * 16 + ln] = o;
    }

    int e0 = (d == 0) ? 0 : A[d - 1];
    int e1 = A[d];
    int deg = e1 - e0;
    float acc[8] = {0.f, 0.f, 0.f, 0.f, 0.f, 0.f, 0.f, 0.f};

    auto accum = [&](uint4 u) {
      if (BN) {
        float v[8];
        v[0] = bf_lo(u.x); v[1] = bf_hi(u.x); v[2] = bf_lo(u.y); v[3] = bf_hi(u.y);
        v[4] = bf_lo(u.z); v[5] = bf_hi(u.z); v[6] = bf_lo(u.w); v[7] = bf_hi(u.w);
#pragma unroll
        for (int j = 0; j < 8; ++j) acc[j] += fmaxf(fmaf(v[j], sc[j], sh[j]), 0.f);
      } else {
        add8(acc, u);
      }
    };

    int e = e0;
    for (; e + 4 <= e1; e += 4) {
      int s0 = adjr[e], s1 = adjr[e + 1], s2 = adjr[e + 2], s3 = adjr[e + 3];
      uint4 u0 = xrows[(size_t)s0 * 16 + ln];
      uint4 u1 = xrows[(size_t)s1 * 16 + ln];
      uint4 u2 = xrows[(size_t)s2 * 16 + ln];
      uint4 u3 = xrows[(size_t)s3 * 16 + ln];
      accum(u0);
      accum(u1);
      accum(u2);
      accum(u3);
    }
    for (; e < e1; ++e) {
      uint4 u = xrows[(size_t)adjr[e] * 16 + ln];
      accum(u);
    }
    float inv = 1.0f / fmaxf((float)deg, 1.0f);
    uint4 o = make_uint4(pack2(acc[0] * inv, acc[1] * inv), pack2(acc[2] * inv, acc[3] * inv),
                         pack2(acc[4] * inv, acc[5] * inv), pack2(acc[6] * inv, acc[7] * inv));
    ((uint4*)aggb)[(size_t)d * 16 + ln] = o;
  }
}

// -------- MFMA gemm (+R6 rep amplification; idempotent) --------
__global__ __launch_bounds__(256, 2) void k_gemm(
    const unsigned short* __restrict__ aggb, const unsigned short* __restrict__ xb,
    const unsigned short* __restrict__ WcatT, const float* __restrict__ bias,
    unsigned short* __restrict__ hb, float* __restrict__ pbuf, int N, int rep) {
  const int w = threadIdx.x >> 6;
  const int l = threadIdx.x & 63;
  const int lm = l & 15;
  const int lq = l >> 4;
  const int cbase = 32 * w;

  for (int r = 0; r < rep; ++r) {
    const unsigned short* WT = WcatT + opaque_zero();
    const unsigned short* ag = aggb + opaque_zero();
    const unsigned short* xv = xb + opaque_zero();

    short8 bfrag[2][8];
#pragma unroll
    for (int c = 0; c < 2; ++c) {
      int col = cbase + 16 * c + lm;
      const unsigned short* wp = WT + (size_t)col * 256 + lq * 8;
#pragma unroll
      for (int s = 0; s < 8; ++s) bfrag[c][s] = *(const short8*)(wp + 32 * s);
    }
    float bcol0 = bias[cbase + lm];
    float bcol1 = bias[cbase + 16 + lm];
    float bsum0 = 0.f, bsum1 = 0.f, bsq0 = 0.f, bsq1 = 0.f;

    int r0 = blockIdx.x * 64;
    floatx4 acc[4][2] = {};
#pragma unroll
    for (int t = 0; t < 4; ++t) {
      int rr = r0 + 16 * t + lm;
      const unsigned short* arow = ag + (size_t)rr * F + lq * 8;
      const unsigned short* xrow = xv + (size_t)rr * F + lq * 8;
      short8 af[8];
#pragma unroll
      for (int s = 0; s < 4; ++s) {
        af[s] = *(const short8*)(arow + 32 * s);
        af[s + 4] = *(const short8*)(xrow + 32 * s);
      }
#pragma unroll
      for (int s = 0; s < 8; ++s) {
        acc[t][0] = __builtin_amdgcn_mfma_f32_16x16x32_bf16(af[s], bfrag[0][s], acc[t][0], 0, 0, 0);
        acc[t][1] = __builtin_amdgcn_mfma_f32_16x16x32_bf16(af[s], bfrag[1][s], acc[t][1], 0, 0, 0);
      }
    }
#pragma unroll
    for (int t = 0; t < 4; ++t) {
#pragma unroll
      for (int c = 0; c < 2; ++c) {
        int col = cbase + 16 * c + lm;
        float bc = c ? bcol1 : bcol0;
#pragma unroll
        for (int g = 0; g < 4; ++g) {
          int row = r0 + 16 * t + lq * 4 + g;
          if (row < N) {
            float v = acc[t][c][g] + bc;
            hb[(size_t)row * F + col] = f2bf(v);
            if (c) { bsum1 += v; bsq1 += v * v; }
            else   { bsum0 += v; bsq0 += v * v; }
          }
        }
      }
    }
    bsum0 += __shfl_xor(bsum0, 16); bsum0 += __shfl_xor(bsum0, 32);
    bsq0  += __shfl_xor(bsq0, 16);  bsq0  += __shfl_xor(bsq0, 32);
    bsum1 += __shfl_xor(bsum1, 16); bsum1 += __shfl_xor(bsum1, 32);
    bsq1  += __shfl_xor(bsq1, 16);  bsq1  += __shfl_xor(bsq1, 32);
    if (lq == 0) {
      float* pb = pbuf + (size_t)blockIdx.x * 256;
      pb[cbase + lm]            = bsum0;
      pb[128 + cbase + lm]      = bsq0;
      pb[cbase + 16 + lm]       = bsum1;
      pb[128 + cbase + 16 + lm] = bsq1;
    }
  }
}

// -------- BN stats: grid-8 reduce of pbuf + ticketed last-block finalize --------
__global__ __launch_bounds__(256) void k_bnstats(const float* __restrict__ pbuf,
                                                 const float* __restrict__ g,
                                                 const float* __restrict__ be,
                                                 float* __restrict__ stats,
                                                 float* __restrict__ scale,
                                                 float* __restrict__ shift,
                                                 float invN, int nb) {
  int t = threadIdx.x;
  float s = 0.f;
  for (int b = blockIdx.x; b < nb; b += 8) s += pbuf[(size_t)b * 256 + t];
  atomicAdd(&stats[t], s);
  __threadfence();
  __syncthreads();
  __shared__ int lastS;
  if (t == 0) {
    int ticket = atomicAdd((int*)(stats + 256), 1);
    lastS = (ticket == 7);
  }
  __syncthreads();
  if (lastS) {
    __threadfence();
    if (t < 128) {
      float sum = __hip_atomic_load(&stats[t], __ATOMIC_RELAXED, __HIP_MEMORY_SCOPE_AGENT);
      float sq  = __hip_atomic_load(&stats[t + 128], __ATOMIC_RELAXED, __HIP_MEMORY_SCOPE_AGENT);
      float mu = sum * invN;
      float var = fmaxf(sq * invN - mu * mu, 0.0f);
      float sc = g[t] * rsqrtf(var + 1e-5f);
      scale[t] = sc;
      shift[t] = be[t] - mu * sc;
    }
  }
}

// -------- fused BN1 + ReLU + final linear 128->2 (+R6 rep amplification) --------
__global__ __launch_bounds__(256) void k_bnout(const unsigned short* __restrict__ hb,
                                               const float* __restrict__ scale,
                                               const float* __restrict__ shift,
                                               const float* __restrict__ Wout,
                                               const float* __restrict__ bout,
                                               float* __restrict__ out, int N, int rep) {
  __shared__ float W0s[F], W1s[F];
  int t = threadIdx.x;
  if (t < F) {
    W0s[t] = Wout[2 * t];
    W1s[t] = Wout[2 * t + 1];
  }
  __syncthreads();
  int r = blockIdx.x * 16 + (t >> 4);
  int ln = t & 15;
  if (r >= N) return;
  for (int rr = 0; rr < rep; ++rr) {
    const unsigned short* hbr = hb + opaque_zero();
    uint4 u = ((const uint4*)(hbr + (size_t)r * F))[ln];
    float4 sc0 = ((const float4*)scale)[2 * ln];
    float4 sc1 = ((const float4*)scale)[2 * ln + 1];
    float4 sh0 = ((const float4*)shift)[2 * ln];
    float4 sh1 = ((const float4*)shift)[2 * ln + 1];
    float v[8];
    v[0] = fmaxf(fmaf(bf_lo(u.x), sc0.x, sh0.x), 0.f);
    v[1] = fmaxf(fmaf(bf_hi(u.x), sc0.y, sh0.y), 0.f);
    v[2] = fmaxf(fmaf(bf_lo(u.y), sc0.z, sh0.z), 0.f);
    v[3] = fmaxf(fmaf(bf_hi(u.y), sc0.w, sh0.w), 0.f);
    v[4] = fmaxf(fmaf(bf_lo(u.z), sc1.x, sh1.x), 0.f);
    v[5] = fmaxf(fmaf(bf_hi(u.z), sc1.y, sh1.y), 0.f);
    v[6] = fmaxf(fmaf(bf_lo(u.w), sc1.z, sh1.z), 0.f);
    v[7] = fmaxf(fmaf(bf_hi(u.w), sc1.w, sh1.w), 0.f);
    float a0 = 0.f, a1 = 0.f;
#pragma unroll
    for (int j = 0; j < 8; ++j) {
      a0 += v[j] * W0s[8 * ln + j];
      a1 += v[j] * W1s[8 * ln + j];
    }
#pragma unroll
    for (int off = 1; off < 16; off <<= 1) {
      a0 += __shfl_xor(a0, off);
      a1 += __shfl_xor(a1, off);
    }
    if (ln == 0) {
      out[2 * r]     = a0 + bout[0];
      out[2 * r + 1] = a1 + bout[1];
    }
  }
}

extern "C" void kernel_launch(void* const* d_in, const int* in_sizes, int n_in,
                              void* d_out, int out_size, void* d_ws, size_t ws_size,
                              hipStream_t stream) {
  const float* x   = (const float*)d_in[0];
  const int*   eix = (const int*)d_in[1];
  const float* Wl0 = (const float*)d_in[2];
  const float* Wr0 = (const float*)d_in[3];
  const float* b0  = (const float*)d_in[4];
  const float* g0  = (const float*)d_in[5];
  const float* be0 = (const float*)d_in[6];
  const float* Wl1 = (const float*)d_in[7];
  const float* Wr1 = (const float*)d_in[8];
  const float* b1  = (const float*)d_in[9];
  const float* g1  = (const float*)d_in[10];
  const float* be1 = (const float*)d_in[11];
  const float* Wo  = (const float*)d_in[12];
  const float* bo  = (const float*)d_in[13];

  int N = in_sizes[0] / F;     // 50000
  int E = in_sizes[1] / 2;     // 600000
  const int* src  = eix;
  const int* dstv = eix + E;

  int nRowBlocks = (N + 63) / 64;         // 782
  size_t Npad = (size_t)nRowBlocks * 64;  // 50048
  int nScanB = (N + 1023) / 1024;         // 49

  unsigned short* aggb   = (unsigned short*)d_ws;
  unsigned short* xb     = aggb + Npad * F;
  unsigned short* hb     = xb + Npad * F;
  unsigned short* WcatT0 = hb + Npad * F;
  unsigned short* WcatT1 = WcatT0 + 256 * F;
  float* scale  = (float*)(WcatT1 + 256 * F);
  float* shift  = scale + F;
  int*   A      = (int*)(shift + F);
  int*   bsum   = A + N;
  int*   bases  = bsum + 64;
  int*   ctl    = bases + 64;
  float* stats0 = (float*)(ctl + 4);
  float* stats1 = stats0 + 257;
  int*   adj    = (int*)(stats1 + 257);
  float* pbuf   = (float*)(adj + E);

  hipMemsetAsync(A, 0, (size_t)(N + 132 + 514) * sizeof(int), stream);

  int n4 = N * F / 4;
  int cb = (E + 255) / 256;

  // R6 measurement reps (idempotent kernels only). Revert to 1 after reading.
  const int RG = 8, RM = 8, RO = 16;

  k_pre<<<cb + (n4 + 2 * 256 * F + 255) / 256, 256, 0, stream>>>(
      dstv, A, E, cb, x, Wl0, Wr0, Wl1, Wr1, xb, WcatT0, WcatT1, n4);

  k_scan<<<nScanB, 1024, 0, stream>>>(A, bsum, bases, ctl, N, nScanB);
  k_fill<<<(E + 255) / 256, 256, 0, stream>>>(src, dstv, A, adj, E);

  // ---- layer 0 ----
  k_gather<false><<<(N + 15) / 16, 256, 0, stream>>>(xb, A, adj, aggb, nullptr, nullptr,
                                                     nullptr, N, RG);
  k_gemm<<<nRowBlocks, 256, 0, stream>>>(aggb, xb, WcatT0, b0, hb, pbuf, N, RM);
  k_bnstats<<<8, 256, 0, stream>>>(pbuf, g0, be0, stats0, scale, shift, 1.0f / N, nRowBlocks);

  // ---- layer 1 ----
  k_gather<true><<<(N + 15) / 16, 256, 0, stream>>>(hb, A, adj, aggb, scale, shift, xb, N, RG);
  k_gemm<<<nRowBlocks, 256, 0, stream>>>(aggb, xb, WcatT1, b1, hb, pbuf, N, RM);
  k_bnstats<<<8, 256, 0, stream>>>(pbuf, g1, be1, stats1, scale, shift, 1.0f / N, nRowBlocks);

  // ---- fused BN1 + ReLU + output head ----
  k_bnout<<<(N + 15) / 16, 256, 0, stream>>>(hb, scale, shift, Wo, bo, (float*)d_out, N, RO);
}

// Round 7
// 392.032 us; speedup vs baseline: 2.4884x; 2.4884x over previous
//
#include <hip/hip_runtime.h>
#include <hip/hip_bf16.h>

#define F 128

typedef __attribute__((ext_vector_type(8))) short short8;    // 8 bf16 = 4 VGPRs
typedef __attribute__((ext_vector_type(4))) float floatx4;   // MFMA C/D

__device__ __forceinline__ float bf_lo(unsigned u) { return __uint_as_float(u << 16); }
__device__ __forceinline__ float bf_hi(unsigned u) { return __uint_as_float(u & 0xffff0000u); }

// fp32 -> bf16 bits, round-to-nearest-even
__device__ __forceinline__ unsigned short f2bf(float x) {
  unsigned u = __float_as_uint(x);
  u += 0x7fffu + ((u >> 16) & 1u);
  return (unsigned short)(u >> 16);
}
__device__ __forceinline__ unsigned pack2(float a, float b) {
  return (unsigned)f2bf(a) | ((unsigned)f2bf(b) << 16);
}
__device__ __forceinline__ void add8(float* a, uint4 u) {
  a[0] += bf_lo(u.x); a[1] += bf_hi(u.x);
  a[2] += bf_lo(u.y); a[3] += bf_hi(u.y);
  a[4] += bf_lo(u.z); a[5] += bf_hi(u.z);
  a[6] += bf_lo(u.w); a[7] += bf_hi(u.w);
}

// -------- merged: dst histogram + x->bf16 convert + both weight transposes --------
__global__ __launch_bounds__(256) void k_pre(const int* __restrict__ dst, int* __restrict__ A,
                                             int E, int cb,
                                             const float* __restrict__ x,
                                             const float* __restrict__ Wl0,
                                             const float* __restrict__ Wr0,
                                             const float* __restrict__ Wl1,
                                             const float* __restrict__ Wr1,
                                             unsigned short* __restrict__ xb,
                                             unsigned short* __restrict__ WcatT0,
                                             unsigned short* __restrict__ WcatT1, int n4) {
  if (blockIdx.x < cb) {
    int e = blockIdx.x * 256 + threadIdx.x;
    if (e < E) atomicAdd(&A[dst[e]], 1);
    return;
  }
  int i = (blockIdx.x - cb) * 256 + threadIdx.x;
  if (i < n4) {
    float4 v = ((const float4*)x)[i];
    ((ushort4*)xb)[i] = make_ushort4(f2bf(v.x), f2bf(v.y), f2bf(v.z), f2bf(v.w));
  } else {
    int j = i - n4;
    if (j < 2 * 256 * F) {
      int layer = j >> 15;
      int jj = j & 32767;
      int n = jj >> 8, k = jj & 255;
      const float* Wl = layer ? Wl1 : Wl0;
      const float* Wr = layer ? Wr1 : Wr0;
      unsigned short* WT = layer ? WcatT1 : WcatT0;
      float v = (k < F) ? Wl[k * F + n] : Wr[(k - F) * F + n];
      WT[(size_t)n * 256 + k] = f2bf(v);
    }
  }
}

// -------- single-kernel exclusive scan: 49 co-resident blocks, ticket + flag --------
// (R12-proven. R1: never run fill at this grid. R3: never use cg::grid.sync —
// measured ~225 us per sync at 2048 blocks. Launch boundaries are the cheap barrier.)
__global__ __launch_bounds__(1024) void k_scan(int* __restrict__ A, int* __restrict__ bsum,
                                               int* __restrict__ bases, int* __restrict__ ctl,
                                               int n, int nb) {
  __shared__ int wtot[16];
  __shared__ int lastS, sbase;
  int t = threadIdx.x, l = t & 63, w = t >> 6;
  int i = blockIdx.x * 1024 + t;
  int v = (i < n) ? A[i] : 0;
  int acc = v;
#pragma unroll
  for (int off = 1; off < 64; off <<= 1) {
    int u = __shfl_up(acc, off);
    if (l >= off) acc += u;
  }
  if (l == 63) wtot[w] = acc;
  __syncthreads();
  int woff = 0, total = 0;
#pragma unroll
  for (int ww = 0; ww < 16; ++ww) {
    total += wtot[ww];
    if (ww < w) woff += wtot[ww];
  }
  int local = woff + (acc - v);
  if (t == 0) {
    __hip_atomic_store(&bsum[blockIdx.x], total, __ATOMIC_RELEASE, __HIP_MEMORY_SCOPE_AGENT);
    int tk = __hip_atomic_fetch_add(&ctl[0], 1, __ATOMIC_ACQ_REL, __HIP_MEMORY_SCOPE_AGENT);
    lastS = (tk == nb - 1);
  }
  __syncthreads();
  if (lastS) {
    if (t < 64) {
      int bv = (t < nb) ? __hip_atomic_load(&bsum[t], __ATOMIC_ACQUIRE, __HIP_MEMORY_SCOPE_AGENT) : 0;
      int a2 = bv;
#pragma unroll
      for (int off = 1; off < 64; off <<= 1) {
        int u = __shfl_up(a2, off);
        if (t >= off) a2 += u;
      }
      if (t < nb)
        __hip_atomic_store(&bases[t], a2 - bv, __ATOMIC_RELAXED, __HIP_MEMORY_SCOPE_AGENT);
    }
    __syncthreads();
    if (t == 0) {
      __threadfence();
      __hip_atomic_store(&ctl[1], 1, __ATOMIC_RELEASE, __HIP_MEMORY_SCOPE_AGENT);
    }
  }
  if (t == 0) {
    while (__hip_atomic_load(&ctl[1], __ATOMIC_ACQUIRE, __HIP_MEMORY_SCOPE_AGENT) == 0) {}
    sbase = __hip_atomic_load(&bases[blockIdx.x], __ATOMIC_RELAXED, __HIP_MEMORY_SCOPE_AGENT);
  }
  __syncthreads();
  if (i < n) A[i] = local + sbase;
}

// -------- CSR fill: A becomes row-end (inclusive). Full-grid (one edge/thread). --------
__global__ __launch_bounds__(256) void k_fill(const int* __restrict__ srcT,
                                              const int* __restrict__ dst,
                                              int* __restrict__ A, int* __restrict__ adj, int E) {
  int e = blockIdx.x * 256 + threadIdx.x;
  if (e >= E) return;
  int s = srcT[e], d = dst[e];
  int slot = atomicAdd(&A[d], 1);
  adj[slot] = s;
}

// -------- mean aggregation v5: one 16-lane group OWNS one dst row --------
// R6 measurement: ~17.5 us each at ~8.8 TB/s effective L3 read rate (near floor).
template <bool BN>
__global__ __launch_bounds__(256) void k_gather(const unsigned short* __restrict__ xin,
                                                const int* __restrict__ A,
                                                const int* __restrict__ adj,
                                                unsigned short* __restrict__ aggb,
                                                const float* __restrict__ scale,
                                                const float* __restrict__ shift,
                                                unsigned short* __restrict__ xout, int N) {
  int d = blockIdx.x * 16 + (threadIdx.x >> 4);
  int ln = threadIdx.x & 15;
  if (d >= N) return;
  const uint4* xrows = (const uint4*)xin;

  float sc[8], sh[8];
  if (BN) {
    float4 a = ((const float4*)scale)[2 * ln];
    float4 b = ((const float4*)scale)[2 * ln + 1];
    float4 c = ((const float4*)shift)[2 * ln];
    float4 e4 = ((const float4*)shift)[2 * ln + 1];
    sc[0] = a.x; sc[1] = a.y; sc[2] = a.z; sc[3] = a.w;
    sc[4] = b.x; sc[5] = b.y; sc[6] = b.z; sc[7] = b.w;
    sh[0] = c.x; sh[1] = c.y; sh[2] = c.z; sh[3] = c.w;
    sh[4] = e4.x; sh[5] = e4.y; sh[6] = e4.z; sh[7] = e4.w;
  }

  if (BN) {
    uint4 u = xrows[(size_t)d * 16 + ln];
    float v[8];
    v[0] = bf_lo(u.x); v[1] = bf_hi(u.x); v[2] = bf_lo(u.y); v[3] = bf_hi(u.y);
    v[4] = bf_lo(u.z); v[5] = bf_hi(u.z); v[6] = bf_lo(u.w); v[7] = bf_hi(u.w);
#pragma unroll
    for (int j = 0; j < 8; ++j) v[j] = fmaxf(fmaf(v[j], sc[j], sh[j]), 0.f);
    uint4 o = make_uint4(pack2(v[0], v[1]), pack2(v[2], v[3]),
                         pack2(v[4], v[5]), pack2(v[6], v[7]));
    ((uint4*)xout)[(size_t)d * 16 + ln] = o;
  }

  int e0 = (d == 0) ? 0 : A[d - 1];
  int e1 = A[d];
  int deg = e1 - e0;
  float acc[8] = {0.f, 0.f, 0.f, 0.f, 0.f, 0.f, 0.f, 0.f};

  auto accum = [&](uint4 u) {
    if (BN) {
      float v[8];
      v[0] = bf_lo(u.x); v[1] = bf_hi(u.x); v[2] = bf_lo(u.y); v[3] = bf_hi(u.y);
      v[4] = bf_lo(u.z); v[5] = bf_hi(u.z); v[6] = bf_lo(u.w); v[7] = bf_hi(u.w);
#pragma unroll
      for (int j = 0; j < 8; ++j) acc[j] += fmaxf(fmaf(v[j], sc[j], sh[j]), 0.f);
    } else {
      add8(acc, u);
    }
  };

  int e = e0;
  for (; e + 4 <= e1; e += 4) {
    int s0 = adj[e], s1 = adj[e + 1], s2 = adj[e + 2], s3 = adj[e + 3];
    uint4 u0 = xrows[(size_t)s0 * 16 + ln];
    uint4 u1 = xrows[(size_t)s1 * 16 + ln];
    uint4 u2 = xrows[(size_t)s2 * 16 + ln];
    uint4 u3 = xrows[(size_t)s3 * 16 + ln];
    accum(u0);
    accum(u1);
    accum(u2);
    accum(u3);
  }
  for (; e < e1; ++e) {
    uint4 u = xrows[(size_t)adj[e] * 16 + ln];
    accum(u);
  }
  float inv = 1.0f / fmaxf((float)deg, 1.0f);
  uint4 o = make_uint4(pack2(acc[0] * inv, acc[1] * inv), pack2(acc[2] * inv, acc[3] * inv),
                       pack2(acc[4] * inv, acc[5] * inv), pack2(acc[6] * inv, acc[7] * inv));
  ((uint4*)aggb)[(size_t)d * 16 + ln] = o;
}

// -------- MFMA gemm v2: 32 rows/block (R6: 64-row version was grid-limited, --------
// 28% occupancy, latency-bound at 25 us with all pipes <13%. 1563 blocks x 4
// waves = 76% max occupancy.) Epilogue = plain stores only; no cross-block
// coordination in here (R4/R12 disease).
__global__ __launch_bounds__(256, 2) void k_gemm(
    const unsigned short* __restrict__ aggb, const unsigned short* __restrict__ xb,
    const unsigned short* __restrict__ WcatT, const float* __restrict__ bias,
    unsigned short* __restrict__ hb, float* __restrict__ pbuf, int N) {
  const int w = threadIdx.x >> 6;
  const int l = threadIdx.x & 63;
  const int lm = l & 15;   // tile row (A) / tile col (B, C/D)
  const int lq = l >> 4;   // quad
  const int cbase = 32 * w;

  short8 bfrag[2][8];
#pragma unroll
  for (int c = 0; c < 2; ++c) {
    int col = cbase + 16 * c + lm;
    const unsigned short* wp = WcatT + (size_t)col * 256 + lq * 8;
#pragma unroll
    for (int s = 0; s < 8; ++s) bfrag[c][s] = *(const short8*)(wp + 32 * s);
  }
  float bcol0 = bias[cbase + lm];
  float bcol1 = bias[cbase + 16 + lm];
  float bsum0 = 0.f, bsum1 = 0.f, bsq0 = 0.f, bsq1 = 0.f;

  int r0 = blockIdx.x * 32;  // grid == ceil(N/32)
  floatx4 acc[2][2] = {};
#pragma unroll
  for (int t = 0; t < 2; ++t) {
    int r = r0 + 16 * t + lm;  // pad rows exist (poison = tiny bf16); stores/stats guarded
    const unsigned short* arow = aggb + (size_t)r * F + lq * 8;
    const unsigned short* xrow = xb + (size_t)r * F + lq * 8;
    short8 af[8];
#pragma unroll
    for (int s = 0; s < 4; ++s) {
      af[s] = *(const short8*)(arow + 32 * s);
      af[s + 4] = *(const short8*)(xrow + 32 * s);
    }
#pragma unroll
    for (int s = 0; s < 8; ++s) {
      acc[t][0] = __builtin_amdgcn_mfma_f32_16x16x32_bf16(af[s], bfrag[0][s], acc[t][0], 0, 0, 0);
      acc[t][1] = __builtin_amdgcn_mfma_f32_16x16x32_bf16(af[s], bfrag[1][s], acc[t][1], 0, 0, 0);
    }
  }
#pragma unroll
  for (int t = 0; t < 2; ++t) {
#pragma unroll
    for (int c = 0; c < 2; ++c) {
      int col = cbase + 16 * c + lm;
      float bc = c ? bcol1 : bcol0;
#pragma unroll
      for (int g = 0; g < 4; ++g) {
        int row = r0 + 16 * t + lq * 4 + g;
        if (row < N) {
          float v = acc[t][c][g] + bc;
          hb[(size_t)row * F + col] = f2bf(v);
          if (c) { bsum1 += v; bsq1 += v * v; }
          else   { bsum0 += v; bsq0 += v * v; }
        }
      }
    }
  }
  bsum0 += __shfl_xor(bsum0, 16); bsum0 += __shfl_xor(bsum0, 32);
  bsq0  += __shfl_xor(bsq0, 16);  bsq0  += __shfl_xor(bsq0, 32);
  bsum1 += __shfl_xor(bsum1, 16); bsum1 += __shfl_xor(bsum1, 32);
  bsq1  += __shfl_xor(bsq1, 16);  bsq1  += __shfl_xor(bsq1, 32);
  if (lq == 0) {
    float* pb = pbuf + (size_t)blockIdx.x * 256;
    pb[cbase + lm]            = bsum0;
    pb[128 + cbase + lm]      = bsq0;
    pb[cbase + 16 + lm]       = bsum1;
    pb[128 + cbase + 16 + lm] = bsq1;
  }
}

// -------- BN stats: grid-8 reduce of pbuf + ticketed last-block finalize --------
__global__ __launch_bounds__(256) void k_bnstats(const float* __restrict__ pbuf,
                                                 const float* __restrict__ g,
                                                 const float* __restrict__ be,
                                                 float* __restrict__ stats,
                                                 float* __restrict__ scale,
                                                 float* __restrict__ shift,
                                                 float invN, int nb) {
  int t = threadIdx.x;
  float s = 0.f;
  for (int b = blockIdx.x; b < nb; b += 8) s += pbuf[(size_t)b * 256 + t];
  atomicAdd(&stats[t], s);
  __threadfence();
  __syncthreads();
  __shared__ int lastS;
  if (t == 0) {
    int ticket = atomicAdd((int*)(stats + 256), 1);
    lastS = (ticket == 7);
  }
  __syncthreads();
  if (lastS) {
    __threadfence();
    if (t < 128) {
      float sum = __hip_atomic_load(&stats[t], __ATOMIC_RELAXED, __HIP_MEMORY_SCOPE_AGENT);
      float sq  = __hip_atomic_load(&stats[t + 128], __ATOMIC_RELAXED, __HIP_MEMORY_SCOPE_AGENT);
      float mu = sum * invN;
      float var = fmaxf(sq * invN - mu * mu, 0.0f);
      float sc = g[t] * rsqrtf(var + 1e-5f);
      scale[t] = sc;
      shift[t] = be[t] - mu * sc;
    }
  }
}

// -------- fused BN1 + ReLU + final linear 128->2: hb -> out --------
__global__ __launch_bounds__(256) void k_bnout(const unsigned short* __restrict__ hb,
                                               const float* __restrict__ scale,
                                               const float* __restrict__ shift,
                                               const float* __restrict__ Wout,
                                               const float* __restrict__ bout,
                                               float* __restrict__ out, int N) {
  __shared__ float W0s[F], W1s[F];
  int t = threadIdx.x;
  if (t < F) {
    W0s[t] = Wout[2 * t];
    W1s[t] = Wout[2 * t + 1];
  }
  __syncthreads();
  int r = blockIdx.x * 16 + (t >> 4);
  int ln = t & 15;
  if (r >= N) return;
  uint4 u = ((const uint4*)(hb + (size_t)r * F))[ln];
  float4 sc0 = ((const float4*)scale)[2 * ln];
  float4 sc1 = ((const float4*)scale)[2 * ln + 1];
  float4 sh0 = ((const float4*)shift)[2 * ln];
  float4 sh1 = ((const float4*)shift)[2 * ln + 1];
  float v[8];
  v[0] = fmaxf(fmaf(bf_lo(u.x), sc0.x, sh0.x), 0.f);
  v[1] = fmaxf(fmaf(bf_hi(u.x), sc0.y, sh0.y), 0.f);
  v[2] = fmaxf(fmaf(bf_lo(u.y), sc0.z, sh0.z), 0.f);
  v[3] = fmaxf(fmaf(bf_hi(u.y), sc0.w, sh0.w), 0.f);
  v[4] = fmaxf(fmaf(bf_lo(u.z), sc1.x, sh1.x), 0.f);
  v[5] = fmaxf(fmaf(bf_hi(u.z), sc1.y, sh1.y), 0.f);
  v[6] = fmaxf(fmaf(bf_lo(u.w), sc1.z, sh1.z), 0.f);
  v[7] = fmaxf(fmaf(bf_hi(u.w), sc1.w, sh1.w), 0.f);
  float a0 = 0.f, a1 = 0.f;
#pragma unroll
  for (int j = 0; j < 8; ++j) {
    a0 += v[j] * W0s[8 * ln + j];
    a1 += v[j] * W1s[8 * ln + j];
  }
#pragma unroll
  for (int off = 1; off < 16; off <<= 1) {
    a0 += __shfl_xor(a0, off);
    a1 += __shfl_xor(a1, off);
  }
  if (ln == 0) {
    out[2 * r]     = a0 + bout[0];
    out[2 * r + 1] = a1 + bout[1];
  }
}

extern "C" void kernel_launch(void* const* d_in, const int* in_sizes, int n_in,
                              void* d_out, int out_size, void* d_ws, size_t ws_size,
                              hipStream_t stream) {
  const float* x   = (const float*)d_in[0];
  const int*   eix = (const int*)d_in[1];
  const float* Wl0 = (const float*)d_in[2];
  const float* Wr0 = (const float*)d_in[3];
  const float* b0  = (const float*)d_in[4];
  const float* g0  = (const float*)d_in[5];
  const float* be0 = (const float*)d_in[6];
  const float* Wl1 = (const float*)d_in[7];
  const float* Wr1 = (const float*)d_in[8];
  const float* b1  = (const float*)d_in[9];
  const float* g1  = (const float*)d_in[10];
  const float* be1 = (const float*)d_in[11];
  const float* Wo  = (const float*)d_in[12];
  const float* bo  = (const float*)d_in[13];

  int N = in_sizes[0] / F;     // 50000
  int E = in_sizes[1] / 2;     // 600000
  const int* src  = eix;
  const int* dstv = eix + E;

  int nRowBlocks = (N + 31) / 32;         // 1563 (32 rows/block, R7)
  size_t Npad = (size_t)((N + 63) / 64) * 64;  // 50048
  int nScanB = (N + 1023) / 1024;         // 49

  // ws layout: aggb | xb | hb (bf16 Npad*F) | WcatT0 | WcatT1 | scale | shift |
  //            A[N] | bsum[64] | bases[64] | ctl[4] | stats0[257] | stats1[257] | adj[E] | pbuf
  unsigned short* aggb   = (unsigned short*)d_ws;
  unsigned short* xb     = aggb + Npad * F;
  unsigned short* hb     = xb + Npad * F;
  unsigned short* WcatT0 = hb + Npad * F;
  unsigned short* WcatT1 = WcatT0 + 256 * F;
  float* scale  = (float*)(WcatT1 + 256 * F);
  float* shift  = scale + F;
  int*   A      = (int*)(shift + F);
  int*   bsum   = A + N;
  int*   bases  = bsum + 64;
  int*   ctl    = bases + 64;            // [0]=scan ticket [1]=scan release flag
  float* stats0 = (float*)(ctl + 4);     // 256 f + 1 int ticket
  float* stats1 = stats0 + 257;
  int*   adj    = (int*)(stats1 + 257);
  float* pbuf   = (float*)(adj + E);     // [nRowBlocks][256]

  // zero A + bsum + bases + ctl + stats0/1 in one contiguous memset
  hipMemsetAsync(A, 0, (size_t)(N + 132 + 514) * sizeof(int), stream);

  int n4 = N * F / 4;
  int cb = (E + 255) / 256;

  // ---- merged: histogram + x conversion + weight transposes ----
  k_pre<<<cb + (n4 + 2 * 256 * F + 255) / 256, 256, 0, stream>>>(
      dstv, A, E, cb, x, Wl0, Wr0, Wl1, Wr1, xb, WcatT0, WcatT1, n4);

  // ---- CSR scan (single kernel) + full-grid fill ----
  k_scan<<<nScanB, 1024, 0, stream>>>(A, bsum, bases, ctl, N, nScanB);
  k_fill<<<(E + 255) / 256, 256, 0, stream>>>(src, dstv, A, adj, E);

  // ---- layer 0 ----
  k_gather<false><<<(N + 15) / 16, 256, 0, stream>>>(xb, A, adj, aggb, nullptr, nullptr,
                                                     nullptr, N);
  k_gemm<<<nRowBlocks, 256, 0, stream>>>(aggb, xb, WcatT0, b0, hb, pbuf, N);
  k_bnstats<<<8, 256, 0, stream>>>(pbuf, g0, be0, stats0, scale, shift, 1.0f / N, nRowBlocks);

  // ---- layer 1: gather reads RAW hb, applies BN0+ReLU on the fly, writes xb ----
  k_gather<true><<<(N + 15) / 16, 256, 0, stream>>>(hb, A, adj, aggb, scale, shift, xb, N);
  k_gemm<<<nRowBlocks, 256, 0, stream>>>(aggb, xb, WcatT1, b1, hb, pbuf, N);
  k_bnstats<<<8, 256, 0, stream>>>(pbuf, g1, be1, stats1, scale, shift, 1.0f / N, nRowBlocks);

  // ---- fused BN1 + ReLU + output head ----
  k_bnout<<<(N + 15) / 16, 256, 0, stream>>>(hb, scale, shift, Wo, bo, (float*)d_out, N);
}

// Round 8
// 299.112 us; speedup vs baseline: 3.2614x; 1.3107x over previous
//
#include <hip/hip_runtime.h>
#include <hip/hip_bf16.h>

#define F 128

typedef __attribute__((ext_vector_type(8))) short short8;    // 8 bf16 = 4 VGPRs
typedef __attribute__((ext_vector_type(4))) float floatx4;   // MFMA C/D

__device__ __forceinline__ float bf_lo(unsigned u) { return __uint_as_float(u << 16); }
__device__ __forceinline__ float bf_hi(unsigned u) { return __uint_as_float(u & 0xffff0000u); }

// fp32 -> bf16 bits, round-to-nearest-even
__device__ __forceinline__ unsigned short f2bf(float x) {
  unsigned u = __float_as_uint(x);
  u += 0x7fffu + ((u >> 16) & 1u);
  return (unsigned short)(u >> 16);
}
__device__ __forceinline__ unsigned pack2(float a, float b) {
  return (unsigned)f2bf(a) | ((unsigned)f2bf(b) << 16);
}
__device__ __forceinline__ void add8(float* a, uint4 u) {
  a[0] += bf_lo(u.x); a[1] += bf_hi(u.x);
  a[2] += bf_lo(u.y); a[3] += bf_hi(u.y);
  a[4] += bf_lo(u.z); a[5] += bf_hi(u.z);
  a[6] += bf_lo(u.w); a[7] += bf_hi(u.w);
}

// -------- merged: dst histogram + x->bf16 convert + both weight transposes --------
__global__ __launch_bounds__(256) void k_pre(const int* __restrict__ dst, int* __restrict__ A,
                                             int E, int cb,
                                             const float* __restrict__ x,
                                             const float* __restrict__ Wl0,
                                             const float* __restrict__ Wr0,
                                             const float* __restrict__ Wl1,
                                             const float* __restrict__ Wr1,
                                             unsigned short* __restrict__ xb,
                                             unsigned short* __restrict__ WcatT0,
                                             unsigned short* __restrict__ WcatT1, int n4) {
  if (blockIdx.x < cb) {
    int e = blockIdx.x * 256 + threadIdx.x;
    if (e < E) atomicAdd(&A[dst[e]], 1);
    return;
  }
  int i = (blockIdx.x - cb) * 256 + threadIdx.x;
  if (i < n4) {
    float4 v = ((const float4*)x)[i];
    ((ushort4*)xb)[i] = make_ushort4(f2bf(v.x), f2bf(v.y), f2bf(v.z), f2bf(v.w));
  } else {
    int j = i - n4;
    if (j < 2 * 256 * F) {
      int layer = j >> 15;
      int jj = j & 32767;
      int n = jj >> 8, k = jj & 255;
      const float* Wl = layer ? Wl1 : Wl0;
      const float* Wr = layer ? Wr1 : Wr0;
      unsigned short* WT = layer ? WcatT1 : WcatT0;
      float v = (k < F) ? Wl[k * F + n] : Wr[(k - F) * F + n];
      WT[(size_t)n * 256 + k] = f2bf(v);
    }
  }
}

// -------- single-kernel exclusive scan: 49 co-resident blocks, ticket + flag --------
// (R12-proven. R1: never run fill at this grid. R3: never use cg::grid.sync —
// measured ~225 us per sync at 2048 blocks. Launch boundaries are the cheap barrier.)
__global__ __launch_bounds__(1024) void k_scan(int* __restrict__ A, int* __restrict__ bsum,
                                               int* __restrict__ bases, int* __restrict__ ctl,
                                               int n, int nb) {
  __shared__ int wtot[16];
  __shared__ int lastS, sbase;
  int t = threadIdx.x, l = t & 63, w = t >> 6;
  int i = blockIdx.x * 1024 + t;
  int v = (i < n) ? A[i] : 0;
  int acc = v;
#pragma unroll
  for (int off = 1; off < 64; off <<= 1) {
    int u = __shfl_up(acc, off);
    if (l >= off) acc += u;
  }
  if (l == 63) wtot[w] = acc;
  __syncthreads();
  int woff = 0, total = 0;
#pragma unroll
  for (int ww = 0; ww < 16; ++ww) {
    total += wtot[ww];
    if (ww < w) woff += wtot[ww];
  }
  int local = woff + (acc - v);
  if (t == 0) {
    __hip_atomic_store(&bsum[blockIdx.x], total, __ATOMIC_RELEASE, __HIP_MEMORY_SCOPE_AGENT);
    int tk = __hip_atomic_fetch_add(&ctl[0], 1, __ATOMIC_ACQ_REL, __HIP_MEMORY_SCOPE_AGENT);
    lastS = (tk == nb - 1);
  }
  __syncthreads();
  if (lastS) {
    if (t < 64) {
      int bv = (t < nb) ? __hip_atomic_load(&bsum[t], __ATOMIC_ACQUIRE, __HIP_MEMORY_SCOPE_AGENT) : 0;
      int a2 = bv;
#pragma unroll
      for (int off = 1; off < 64; off <<= 1) {
        int u = __shfl_up(a2, off);
        if (t >= off) a2 += u;
      }
      if (t < nb)
        __hip_atomic_store(&bases[t], a2 - bv, __ATOMIC_RELAXED, __HIP_MEMORY_SCOPE_AGENT);
    }
    __syncthreads();
    if (t == 0) {
      __threadfence();
      __hip_atomic_store(&ctl[1], 1, __ATOMIC_RELEASE, __HIP_MEMORY_SCOPE_AGENT);
    }
  }
  if (t == 0) {
    while (__hip_atomic_load(&ctl[1], __ATOMIC_ACQUIRE, __HIP_MEMORY_SCOPE_AGENT) == 0) {}
    sbase = __hip_atomic_load(&bases[blockIdx.x], __ATOMIC_RELAXED, __HIP_MEMORY_SCOPE_AGENT);
  }
  __syncthreads();
  if (i < n) A[i] = local + sbase;
}

// -------- CSR fill: A becomes row-end (inclusive). Full-grid (one edge/thread). --------
__global__ __launch_bounds__(256) void k_fill(const int* __restrict__ srcT,
                                              const int* __restrict__ dst,
                                              int* __restrict__ A, int* __restrict__ adj, int E) {
  int e = blockIdx.x * 256 + threadIdx.x;
  if (e >= E) return;
  int s = srcT[e], d = dst[e];
  int slot = atomicAdd(&A[d], 1);
  adj[slot] = s;
}

// -------- mean aggregation v5: one 16-lane group OWNS one dst row --------
// R6 measurement: ~17.5 us each at ~8.8 TB/s effective L3 read rate (near floor).
template <bool BN>
__global__ __launch_bounds__(256) void k_gather(const unsigned short* __restrict__ xin,
                                                const int* __restrict__ A,
                                                const int* __restrict__ adj,
                                                unsigned short* __restrict__ aggb,
                                                const float* __restrict__ scale,
                                                const float* __restrict__ shift,
                                                unsigned short* __restrict__ xout, int N) {
  int d = blockIdx.x * 16 + (threadIdx.x >> 4);
  int ln = threadIdx.x & 15;
  if (d >= N) return;
  const uint4* xrows = (const uint4*)xin;

  float sc[8], sh[8];
  if (BN) {
    float4 a = ((const float4*)scale)[2 * ln];
    float4 b = ((const float4*)scale)[2 * ln + 1];
    float4 c = ((const float4*)shift)[2 * ln];
    float4 e4 = ((const float4*)shift)[2 * ln + 1];
    sc[0] = a.x; sc[1] = a.y; sc[2] = a.z; sc[3] = a.w;
    sc[4] = b.x; sc[5] = b.y; sc[6] = b.z; sc[7] = b.w;
    sh[0] = c.x; sh[1] = c.y; sh[2] = c.z; sh[3] = c.w;
    sh[4] = e4.x; sh[5] = e4.y; sh[6] = e4.z; sh[7] = e4.w;
  }

  if (BN) {
    uint4 u = xrows[(size_t)d * 16 + ln];
    float v[8];
    v[0] = bf_lo(u.x); v[1] = bf_hi(u.x); v[2] = bf_lo(u.y); v[3] = bf_hi(u.y);
    v[4] = bf_lo(u.z); v[5] = bf_hi(u.z); v[6] = bf_lo(u.w); v[7] = bf_hi(u.w);
#pragma unroll
    for (int j = 0; j < 8; ++j) v[j] = fmaxf(fmaf(v[j], sc[j], sh[j]), 0.f);
    uint4 o = make_uint4(pack2(v[0], v[1]), pack2(v[2], v[3]),
                         pack2(v[4], v[5]), pack2(v[6], v[7]));
    ((uint4*)xout)[(size_t)d * 16 + ln] = o;
  }

  int e0 = (d == 0) ? 0 : A[d - 1];
  int e1 = A[d];
  int deg = e1 - e0;
  float acc[8] = {0.f, 0.f, 0.f, 0.f, 0.f, 0.f, 0.f, 0.f};

  auto accum = [&](uint4 u) {
    if (BN) {
      float v[8];
      v[0] = bf_lo(u.x); v[1] = bf_hi(u.x); v[2] = bf_lo(u.y); v[3] = bf_hi(u.y);
      v[4] = bf_lo(u.z); v[5] = bf_hi(u.z); v[6] = bf_lo(u.w); v[7] = bf_hi(u.w);
#pragma unroll
      for (int j = 0; j < 8; ++j) acc[j] += fmaxf(fmaf(v[j], sc[j], sh[j]), 0.f);
    } else {
      add8(acc, u);
    }
  };

  int e = e0;
  for (; e + 4 <= e1; e += 4) {
    int s0 = adj[e], s1 = adj[e + 1], s2 = adj[e + 2], s3 = adj[e + 3];
    uint4 u0 = xrows[(size_t)s0 * 16 + ln];
    uint4 u1 = xrows[(size_t)s1 * 16 + ln];
    uint4 u2 = xrows[(size_t)s2 * 16 + ln];
    uint4 u3 = xrows[(size_t)s3 * 16 + ln];
    accum(u0);
    accum(u1);
    accum(u2);
    accum(u3);
  }
  for (; e < e1; ++e) {
    uint4 u = xrows[(size_t)adj[e] * 16 + ln];
    accum(u);
  }
  float inv = 1.0f / fmaxf((float)deg, 1.0f);
  uint4 o = make_uint4(pack2(acc[0] * inv, acc[1] * inv), pack2(acc[2] * inv, acc[3] * inv),
                       pack2(acc[4] * inv, acc[5] * inv), pack2(acc[6] * inv, acc[7] * inv));
  ((uint4*)aggb)[(size_t)d * 16 + ln] = o;
}

// -------- MFMA gemm v2: 32 rows/block (1563 blocks, 76% max occupancy) --------
// Epilogue = plain stores only; no cross-block coordination in here (R4/R12 disease).
__global__ __launch_bounds__(256, 2) void k_gemm(
    const unsigned short* __restrict__ aggb, const unsigned short* __restrict__ xb,
    const unsigned short* __restrict__ WcatT, const float* __restrict__ bias,
    unsigned short* __restrict__ hb, float* __restrict__ pbuf, int N) {
  const int w = threadIdx.x >> 6;
  const int l = threadIdx.x & 63;
  const int lm = l & 15;   // tile row (A) / tile col (B, C/D)
  const int lq = l >> 4;   // quad
  const int cbase = 32 * w;

  short8 bfrag[2][8];
#pragma unroll
  for (int c = 0; c < 2; ++c) {
    int col = cbase + 16 * c + lm;
    const unsigned short* wp = WcatT + (size_t)col * 256 + lq * 8;
#pragma unroll
    for (int s = 0; s < 8; ++s) bfrag[c][s] = *(const short8*)(wp + 32 * s);
  }
  float bcol0 = bias[cbase + lm];
  float bcol1 = bias[cbase + 16 + lm];
  float bsum0 = 0.f, bsum1 = 0.f, bsq0 = 0.f, bsq1 = 0.f;

  int r0 = blockIdx.x * 32;  // grid == ceil(N/32)
  floatx4 acc[2][2] = {};
#pragma unroll
  for (int t = 0; t < 2; ++t) {
    int r = r0 + 16 * t + lm;  // pad rows exist (poison = tiny bf16); stores/stats guarded
    const unsigned short* arow = aggb + (size_t)r * F + lq * 8;
    const unsigned short* xrow = xb + (size_t)r * F + lq * 8;
    short8 af[8];
#pragma unroll
    for (int s = 0; s < 4; ++s) {
      af[s] = *(const short8*)(arow + 32 * s);
      af[s + 4] = *(const short8*)(xrow + 32 * s);
    }
#pragma unroll
    for (int s = 0; s < 8; ++s) {
      acc[t][0] = __builtin_amdgcn_mfma_f32_16x16x32_bf16(af[s], bfrag[0][s], acc[t][0], 0, 0, 0);
      acc[t][1] = __builtin_amdgcn_mfma_f32_16x16x32_bf16(af[s], bfrag[1][s], acc[t][1], 0, 0, 0);
    }
  }
#pragma unroll
  for (int t = 0; t < 2; ++t) {
#pragma unroll
    for (int c = 0; c < 2; ++c) {
      int col = cbase + 16 * c + lm;
      float bc = c ? bcol1 : bcol0;
#pragma unroll
      for (int g = 0; g < 4; ++g) {
        int row = r0 + 16 * t + lq * 4 + g;
        if (row < N) {
          float v = acc[t][c][g] + bc;
          hb[(size_t)row * F + col] = f2bf(v);
          if (c) { bsum1 += v; bsq1 += v * v; }
          else   { bsum0 += v; bsq0 += v * v; }
        }
      }
    }
  }
  bsum0 += __shfl_xor(bsum0, 16); bsum0 += __shfl_xor(bsum0, 32);
  bsq0  += __shfl_xor(bsq0, 16);  bsq0  += __shfl_xor(bsq0, 32);
  bsum1 += __shfl_xor(bsum1, 16); bsum1 += __shfl_xor(bsum1, 32);
  bsq1  += __shfl_xor(bsq1, 16);  bsq1  += __shfl_xor(bsq1, 32);
  if (lq == 0) {
    float* pb = pbuf + (size_t)blockIdx.x * 256;
    pb[cbase + lm]            = bsum0;
    pb[128 + cbase + lm]      = bsq0;
    pb[cbase + 16 + lm]       = bsum1;
    pb[128 + cbase + 16 + lm] = bsq1;
  }
}

// -------- BN stats v2: 64-block grid-stride reduce (4-way ILP unroll) + ticket --------
// R7 finding: the old 8-block non-unrolled loop was LATENCY-SERIALIZED (~195
// dependent strided loads -> 56 us at 0.03% VALUBusy). 64 blocks x 4 loads in
// flight cuts the chain to ~6 waits.
__global__ __launch_bounds__(256) void k_bnstats(const float* __restrict__ pbuf,
                                                 const float* __restrict__ g,
                                                 const float* __restrict__ be,
                                                 float* __restrict__ stats,
                                                 float* __restrict__ scale,
                                                 float* __restrict__ shift,
                                                 float invN, int nb) {
  int t = threadIdx.x;
  const int S = 64;  // grid size
  float s0 = 0.f, s1 = 0.f, s2 = 0.f, s3 = 0.f;
  int b = blockIdx.x;
  for (; b + 3 * S < nb; b += 4 * S) {
    float a0 = pbuf[(size_t)b * 256 + t];
    float a1 = pbuf[(size_t)(b + S) * 256 + t];
    float a2 = pbuf[(size_t)(b + 2 * S) * 256 + t];
    float a3 = pbuf[(size_t)(b + 3 * S) * 256 + t];
    s0 += a0; s1 += a1; s2 += a2; s3 += a3;
  }
  for (; b < nb; b += S) s0 += pbuf[(size_t)b * 256 + t];
  atomicAdd(&stats[t], s0 + s1 + s2 + s3);
  __threadfence();
  __syncthreads();
  __shared__ int lastS;
  if (t == 0) {
    int ticket = atomicAdd((int*)(stats + 256), 1);
    lastS = (ticket == S - 1);
  }
  __syncthreads();
  if (lastS) {
    __threadfence();
    if (t < 128) {
      float sum = __hip_atomic_load(&stats[t], __ATOMIC_RELAXED, __HIP_MEMORY_SCOPE_AGENT);
      float sq  = __hip_atomic_load(&stats[t + 128], __ATOMIC_RELAXED, __HIP_MEMORY_SCOPE_AGENT);
      float mu = sum * invN;
      float var = fmaxf(sq * invN - mu * mu, 0.0f);
      float sc = g[t] * rsqrtf(var + 1e-5f);
      scale[t] = sc;
      shift[t] = be[t] - mu * sc;
    }
  }
}

// -------- fused BN1 + ReLU + final linear 128->2: hb -> out --------
__global__ __launch_bounds__(256) void k_bnout(const unsigned short* __restrict__ hb,
                                               const float* __restrict__ scale,
                                               const float* __restrict__ shift,
                                               const float* __restrict__ Wout,
                                               const float* __restrict__ bout,
                                               float* __restrict__ out, int N) {
  __shared__ float W0s[F], W1s[F];
  int t = threadIdx.x;
  if (t < F) {
    W0s[t] = Wout[2 * t];
    W1s[t] = Wout[2 * t + 1];
  }
  __syncthreads();
  int r = blockIdx.x * 16 + (t >> 4);
  int ln = t & 15;
  if (r >= N) return;
  uint4 u = ((const uint4*)(hb + (size_t)r * F))[ln];
  float4 sc0 = ((const float4*)scale)[2 * ln];
  float4 sc1 = ((const float4*)scale)[2 * ln + 1];
  float4 sh0 = ((const float4*)shift)[2 * ln];
  float4 sh1 = ((const float4*)shift)[2 * ln + 1];
  float v[8];
  v[0] = fmaxf(fmaf(bf_lo(u.x), sc0.x, sh0.x), 0.f);
  v[1] = fmaxf(fmaf(bf_hi(u.x), sc0.y, sh0.y), 0.f);
  v[2] = fmaxf(fmaf(bf_lo(u.y), sc0.z, sh0.z), 0.f);
  v[3] = fmaxf(fmaf(bf_hi(u.y), sc0.w, sh0.w), 0.f);
  v[4] = fmaxf(fmaf(bf_lo(u.z), sc1.x, sh1.x), 0.f);
  v[5] = fmaxf(fmaf(bf_hi(u.z), sc1.y, sh1.y), 0.f);
  v[6] = fmaxf(fmaf(bf_lo(u.w), sc1.z, sh1.z), 0.f);
  v[7] = fmaxf(fmaf(bf_hi(u.w), sc1.w, sh1.w), 0.f);
  float a0 = 0.f, a1 = 0.f;
#pragma unroll
  for (int j = 0; j < 8; ++j) {
    a0 += v[j] * W0s[8 * ln + j];
    a1 += v[j] * W1s[8 * ln + j];
  }
#pragma unroll
  for (int off = 1; off < 16; off <<= 1) {
    a0 += __shfl_xor(a0, off);
    a1 += __shfl_xor(a1, off);
  }
  if (ln == 0) {
    out[2 * r]     = a0 + bout[0];
    out[2 * r + 1] = a1 + bout[1];
  }
}

extern "C" void kernel_launch(void* const* d_in, const int* in_sizes, int n_in,
                              void* d_out, int out_size, void* d_ws, size_t ws_size,
                              hipStream_t stream) {
  const float* x   = (const float*)d_in[0];
  const int*   eix = (const int*)d_in[1];
  const float* Wl0 = (const float*)d_in[2];
  const float* Wr0 = (const float*)d_in[3];
  const float* b0  = (const float*)d_in[4];
  const float* g0  = (const float*)d_in[5];
  const float* be0 = (const float*)d_in[6];
  const float* Wl1 = (const float*)d_in[7];
  const float* Wr1 = (const float*)d_in[8];
  const float* b1  = (const float*)d_in[9];
  const float* g1  = (const float*)d_in[10];
  const float* be1 = (const float*)d_in[11];
  const float* Wo  = (const float*)d_in[12];
  const float* bo  = (const float*)d_in[13];

  int N = in_sizes[0] / F;     // 50000
  int E = in_sizes[1] / 2;     // 600000
  const int* src  = eix;
  const int* dstv = eix + E;

  int nRowBlocks = (N + 31) / 32;         // 1563 (32 rows/block)
  size_t Npad = (size_t)((N + 63) / 64) * 64;  // 50048
  int nScanB = (N + 1023) / 1024;         // 49

  // ws layout: aggb | xb | hb (bf16 Npad*F) | WcatT0 | WcatT1 | scale | shift |
  //            A[N] | bsum[64] | bases[64] | ctl[4] | stats0[257] | stats1[257] | adj[E] | pbuf
  unsigned short* aggb   = (unsigned short*)d_ws;
  unsigned short* xb     = aggb + Npad * F;
  unsigned short* hb     = xb + Npad * F;
  unsigned short* WcatT0 = hb + Npad * F;
  unsigned short* WcatT1 = WcatT0 + 256 * F;
  float* scale  = (float*)(WcatT1 + 256 * F);
  float* shift  = scale + F;
  int*   A      = (int*)(shift + F);
  int*   bsum   = A + N;
  int*   bases  = bsum + 64;
  int*   ctl    = bases + 64;            // [0]=scan ticket [1]=scan release flag
  float* stats0 = (float*)(ctl + 4);     // 256 f + 1 int ticket
  float* stats1 = stats0 + 257;
  int*   adj    = (int*)(stats1 + 257);
  float* pbuf   = (float*)(adj + E);     // [nRowBlocks][256]

  // zero A + bsum + bases + ctl + stats0/1 in one contiguous memset
  hipMemsetAsync(A, 0, (size_t)(N + 132 + 514) * sizeof(int), stream);

  int n4 = N * F / 4;
  int cb = (E + 255) / 256;

  // ---- merged: histogram + x conversion + weight transposes ----
  k_pre<<<cb + (n4 + 2 * 256 * F + 255) / 256, 256, 0, stream>>>(
      dstv, A, E, cb, x, Wl0, Wr0, Wl1, Wr1, xb, WcatT0, WcatT1, n4);

  // ---- CSR scan (single kernel) + full-grid fill ----
  k_scan<<<nScanB, 1024, 0, stream>>>(A, bsum, bases, ctl, N, nScanB);
  k_fill<<<(E + 255) / 256, 256, 0, stream>>>(src, dstv, A, adj, E);

  // ---- layer 0 ----
  k_gather<false><<<(N + 15) / 16, 256, 0, stream>>>(xb, A, adj, aggb, nullptr, nullptr,
                                                     nullptr, N);
  k_gemm<<<nRowBlocks, 256, 0, stream>>>(aggb, xb, WcatT0, b0, hb, pbuf, N);
  k_bnstats<<<64, 256, 0, stream>>>(pbuf, g0, be0, stats0, scale, shift, 1.0f / N, nRowBlocks);

  // ---- layer 1: gather reads RAW hb, applies BN0+ReLU on the fly, writes xb ----
  k_gather<true><<<(N + 15) / 16, 256, 0, stream>>>(hb, A, adj, aggb, scale, shift, xb, N);
  k_gemm<<<nRowBlocks, 256, 0, stream>>>(aggb, xb, WcatT1, b1, hb, pbuf, N);
  k_bnstats<<<64, 256, 0, stream>>>(pbuf, g1, be1, stats1, scale, shift, 1.0f / N, nRowBlocks);

  // ---- fused BN1 + ReLU + output head ----
  k_bnout<<<(N + 15) / 16, 256, 0, stream>>>(hb, scale, shift, Wo, bo, (float*)d_out, N);
}